// Round 11
// baseline (210.523 us; speedup 1.0000x reference)
//
#include <hip/hip_runtime.h>

// FraudDetectionModel: out = Linear(2,1)( chain_{l=0..31} [ tanh(h@W_l^T+b_l)*scale_l+shift_l ] (x) )
// B = 8388608 independent rows of a 2-dim recurrence.
//
// g-substitution: track g = 1/(exp2(c*z)+1), c = 2*log2(e); tanh = 1-2g folds into
// the next affine: M_{l+1} = -2c W_{l+1} diag(s_l), C_{l+1} = c(b_{l+1}+W_{l+1}(s_l+t_l)).
//
// Round-11: EXACT R6 structure (8-way batched rcp, SoA arrays, homogeneous loops)
// with ONE change: __launch_bounds__(256,8) -> (256,4).
// R6 measured 143.6 us with WRITE_SIZE=108 MB: the (256,8) clause caps the
// allocator at 32 VGPR (proven R7->R8/R10) and the tree's +14 live temps spilled.
// Clean model at no-spill, t_eff~11 (calibrated R10: busy fits 2*nV+11*nT to 1%):
//   per 4 rows/layer: tree = 45 V + 9 T = 189 cyc  vs  pair = 36 V + 12 T = 204 cyc
//   -> busy 86.4 -> ~80 us, dur ~100 (vs R10's 106.5).
// Decision rule: dur >= 106 kills the batched-tree family; R10 is champion and
// the serial-pipe arithmetic floor (busy model fits measured busy within 1%)
// is the roofline.

constexpr int LAYERS = 32;
constexpr int BLOCK  = 256;
constexpr int R4     = 8;   // float4 x-loads per thread = 16 rows/thread = 4 batches of 4 rows

__device__ __forceinline__ float fast_exp2(float x) {
#if __has_builtin(__builtin_amdgcn_exp2f)
    return __builtin_amdgcn_exp2f(x);
#else
    return exp2f(x);
#endif
}
__device__ __forceinline__ float fast_rcp(float x) {
#if __has_builtin(__builtin_amdgcn_rcpf)
    return __builtin_amdgcn_rcpf(x);
#else
    return 1.0f / x;
#endif
}

// 8 sigmoid-denominators -> 8 g = 1/(exp2(zs)+1) with a single v_rcp.
// Product tree up (7 mul), rcp at root, inverse tree down (6 mul), leaves (8 mul).
// Overflow: prod(d_i) < 2^128 needs sum of positive zs > 128 (~15 sigma); R6 ran
// this exact tree on the full fixed dataset with absmax 0.0 -> empirically safe.
__device__ __forceinline__ void batch_g8(const float zs[8], float g[8]) {
    float d0 = fast_exp2(zs[0]) + 1.0f;
    float d1 = fast_exp2(zs[1]) + 1.0f;
    float d2 = fast_exp2(zs[2]) + 1.0f;
    float d3 = fast_exp2(zs[3]) + 1.0f;
    float d4 = fast_exp2(zs[4]) + 1.0f;
    float d5 = fast_exp2(zs[5]) + 1.0f;
    float d6 = fast_exp2(zs[6]) + 1.0f;
    float d7 = fast_exp2(zs[7]) + 1.0f;
    float p01 = d0*d1, p23 = d2*d3, p45 = d4*d5, p67 = d6*d7;
    float q0  = p01*p23, q1 = p45*p67;
    float R   = fast_rcp(q0*q1);
    float rA  = R*q1;            // 1/q0
    float rB  = R*q0;            // 1/q1
    float r01 = rA*p23;          // 1/p01
    float r23 = rA*p01;          // 1/p23
    float r45 = rB*p67;          // 1/p45
    float r67 = rB*p45;          // 1/p67
    g[0] = r01*d1; g[1] = r01*d0;
    g[2] = r23*d3; g[3] = r23*d2;
    g[4] = r45*d5; g[5] = r45*d4;
    g[6] = r67*d7; g[7] = r67*d6;
}

__global__ __launch_bounds__(BLOCK, 4) void fraud_fwd(
        const float* __restrict__ x,      // [B,2]
        const float* __restrict__ W,      // [32,2,2]
        const float* __restrict__ b,      // [32,2]
        const float* __restrict__ scale,  // [32,2]
        const float* __restrict__ shift,  // [32,2]
        const float* __restrict__ w_out,  // [1,2]
        const float* __restrict__ b_out,  // [1]
        float* __restrict__ out)          // [B,1]
{
    __shared__ float sP[LAYERS * 8];  // per layer: m00,m01,m10,m11,C0,C1,pad,pad (32B stride)
    __shared__ float sF[4];           // Mo0, Mo1, Co, pad

    const int t = threadIdx.x;
    const float c = 2.885390081777927f;  // 2*log2(e)

    if (t < LAYERS) {
        float w00 = W[t*4+0], w01 = W[t*4+1], w10 = W[t*4+2], w11 = W[t*4+3];
        float b0 = b[t*2+0], b1 = b[t*2+1];
        float m00, m01, m10, m11, C0, C1;
        if (t > 0) {
            float s0 = scale[(t-1)*2+0], s1 = scale[(t-1)*2+1];
            float u0 = s0 + shift[(t-1)*2+0], u1 = s1 + shift[(t-1)*2+1];
            C0 = c * (b0 + w00*u0 + w01*u1);
            C1 = c * (b1 + w10*u0 + w11*u1);
            float k = -2.0f * c;
            m00 = k*w00*s0; m01 = k*w01*s1;
            m10 = k*w10*s0; m11 = k*w11*s1;
        } else {
            C0 = c*b0; C1 = c*b1;
            m00 = c*w00; m01 = c*w01; m10 = c*w10; m11 = c*w11;
        }
        sP[t*8+0] = m00; sP[t*8+1] = m01;
        sP[t*8+2] = m10; sP[t*8+3] = m11;
        sP[t*8+4] = C0;  sP[t*8+5] = C1;
        sP[t*8+6] = 0.f; sP[t*8+7] = 0.f;
    } else if (t == LAYERS) {
        float s0 = scale[31*2+0], s1 = scale[31*2+1];
        float u0 = s0 + shift[31*2+0], u1 = s1 + shift[31*2+1];
        float wo0 = w_out[0], wo1 = w_out[1];
        sF[0] = -2.0f * wo0 * s0;
        sF[1] = -2.0f * wo1 * s1;
        sF[2] = b_out[0] + wo0*u0 + wo1*u1;
        sF[3] = 0.f;
    }
    __syncthreads();

    const float4* __restrict__ xv = (const float4*)x;   // one float4 = 2 rows
    float2*       __restrict__ ov = (float2*)out;       // one float2 = 2 rows' outputs
    const int base4 = blockIdx.x * (BLOCK * R4) + t;    // block-interleaved -> coalesced

    float gx[2*R4], gy[2*R4];

    // Layer 0: from raw x. Batch 4 rows (2 float4) per tree.
    {
        const float4 m0 = *(const float4*)&sP[0];
        const float C0 = sP[4], C1 = sP[5];
        #pragma unroll
        for (int bi = 0; bi < R4/2; ++bi) {        // 4 batches of 4 rows
            float4 a0 = xv[base4 + (2*bi+0)*BLOCK];
            float4 a1 = xv[base4 + (2*bi+1)*BLOCK];
            float zs[8], g[8];
            zs[0] = fmaf(a0.x, m0.x, fmaf(a0.y, m0.y, C0));
            zs[1] = fmaf(a0.x, m0.z, fmaf(a0.y, m0.w, C1));
            zs[2] = fmaf(a0.z, m0.x, fmaf(a0.w, m0.y, C0));
            zs[3] = fmaf(a0.z, m0.z, fmaf(a0.w, m0.w, C1));
            zs[4] = fmaf(a1.x, m0.x, fmaf(a1.y, m0.y, C0));
            zs[5] = fmaf(a1.x, m0.z, fmaf(a1.y, m0.w, C1));
            zs[6] = fmaf(a1.z, m0.x, fmaf(a1.w, m0.y, C0));
            zs[7] = fmaf(a1.z, m0.z, fmaf(a1.w, m0.w, C1));
            batch_g8(zs, g);
            #pragma unroll
            for (int r = 0; r < 4; ++r) {
                gx[4*bi + r] = g[2*r+0];
                gy[4*bi + r] = g[2*r+1];
            }
        }
    }

    // Layers 1..31: 4 batches of 4 rows per layer, one rcp per batch.
    #pragma unroll 4
    for (int l = 1; l < LAYERS; ++l) {
        const float4 m  = *(const float4*)&sP[l*8];
        const float C0 = sP[l*8+4];
        const float C1 = sP[l*8+5];
        #pragma unroll
        for (int bi = 0; bi < 4; ++bi) {
            float zs[8], g[8];
            #pragma unroll
            for (int r = 0; r < 4; ++r) {
                float ga = gx[4*bi + r], gb = gy[4*bi + r];
                zs[2*r+0] = fmaf(ga, m.x, fmaf(gb, m.y, C0));
                zs[2*r+1] = fmaf(ga, m.z, fmaf(gb, m.w, C1));
            }
            batch_g8(zs, g);
            #pragma unroll
            for (int r = 0; r < 4; ++r) {
                gx[4*bi + r] = g[2*r+0];
                gy[4*bi + r] = g[2*r+1];
            }
        }
    }

    // Output fold: out = Co + Mo0*gx + Mo1*gy
    const float Mo0 = sF[0], Mo1 = sF[1], Co = sF[2];
    #pragma unroll
    for (int i = 0; i < R4; ++i) {
        float2 o;
        o.x = fmaf(gx[2*i+0], Mo0, fmaf(gy[2*i+0], Mo1, Co));
        o.y = fmaf(gx[2*i+1], Mo0, fmaf(gy[2*i+1], Mo1, Co));
        ov[base4 + i*BLOCK] = o;
    }
}

extern "C" void kernel_launch(void* const* d_in, const int* in_sizes, int n_in,
                              void* d_out, int out_size, void* d_ws, size_t ws_size,
                              hipStream_t stream) {
    const float* x     = (const float*)d_in[0];
    const float* W     = (const float*)d_in[1];
    const float* b     = (const float*)d_in[2];
    const float* scale = (const float*)d_in[3];
    const float* shift = (const float*)d_in[4];
    const float* w_out = (const float*)d_in[5];
    const float* b_out = (const float*)d_in[6];
    float* out = (float*)d_out;

    const int B = in_sizes[0] / 2;               // 8388608
    const int rows_per_block = BLOCK * R4 * 2;   // 4096
    const int blocks = B / rows_per_block;       // 2048

    fraud_fwd<<<blocks, BLOCK, 0, stream>>>(x, W, b, scale, shift, w_out, b_out, out);
}

// Round 15
// 186.087 us; speedup vs baseline: 1.1313x; 1.1313x over previous
//
#include <hip/hip_runtime.h>

// FraudDetectionModel: out = Linear(2,1)( chain_{l=0..31} [ tanh(h@W_l^T+b_l)*scale_l+shift_l ] (x) )
// B = 8388608 independent rows of a 2-dim recurrence.
//
// g-substitution: track g = 1/(exp2(c*z)+1), c = 2*log2(e); tanh = 1-2g folds into
// the next affine: M_{l+1} = -2c W_{l+1} diag(s_l), C_{l+1} = c(b_{l+1}+W_{l+1}(s_l+t_l)).
// Pair-batched rcp per row (CHAMPION dataflow, R10 = 106.5 us, busy fits
// 2*nV + 11*nT serial-issue model within 1%).
//
// Round-12 change (this kernel): fold the two +1.0 adds and one mul into FMAs:
//   d1 = e1+1;  p = fma(e0,d1,d1) = (e0+1)(e1+1);  r = rcp(p);
//   gx = d1*r = 1/d0;  gy = fma(e0,r,r) = (e0+1)*r = 1/d1.
// 9 V + 3 T -> 8 V + 3 T per row-layer (-4% busy). Chain depth and the 16
// independent per-row chains (which keep t_eff at ~11 vs the tree's ~19) are
// unchanged.
//
// Settled by experiment, do not revisit:
//  - (256,8) caps allocator at 32 VGPR -> spill (R5/R6/R7); (256,4) is correct.
//  - rcp-sharing trees (4/8-way) lose: latency exposure beats op savings (R8/R11).
//  - source-level phase ordering is a no-op; hipcc reschedules (R9).

constexpr int LAYERS = 32;
constexpr int BLOCK  = 256;
constexpr int R4     = 8;   // float4 x-loads per thread = 16 rows/thread

__device__ __forceinline__ float fast_exp2(float x) {
#if __has_builtin(__builtin_amdgcn_exp2f)
    return __builtin_amdgcn_exp2f(x);
#else
    return exp2f(x);
#endif
}
__device__ __forceinline__ float fast_rcp(float x) {
#if __has_builtin(__builtin_amdgcn_rcpf)
    return __builtin_amdgcn_rcpf(x);
#else
    return 1.0f / x;
#endif
}

// One layer on one row: (ga,gb) -> (gx,gy) through zs = M*(ga,gb) + C.
// 8 VALU + 3 trans. r = 1/((e0+1)(e1+1)); gx = (e1+1)r = 1/d0; gy = (e0+1)r = 1/d1.
// zs -> -inf: e=0 -> d1=1, r=1/d0, gx=1/d0, gy=1 (correct). Overflow (zs>128)
// unreachable: |z| <~ 17 for this data (empirically absmax 0.0 since R3).
__device__ __forceinline__ void layer_g(float ga, float gb,
                                        const float4 m, float C0, float C1,
                                        float& gx, float& gy) {
    float zs0 = fmaf(ga, m.x, fmaf(gb, m.y, C0));
    float zs1 = fmaf(ga, m.z, fmaf(gb, m.w, C1));
    float e0 = fast_exp2(zs0);
    float e1 = fast_exp2(zs1);
    float d1 = e1 + 1.0f;
    float p  = fmaf(e0, d1, d1);     // (e0+1)*(e1+1) = d0*d1
    float r  = fast_rcp(p);
    gx = d1 * r;                     // 1/d0
    gy = fmaf(e0, r, r);             // d0*r = 1/d1
}

__global__ __launch_bounds__(BLOCK, 4) void fraud_fwd(
        const float* __restrict__ x,      // [B,2]
        const float* __restrict__ W,      // [32,2,2]
        const float* __restrict__ b,      // [32,2]
        const float* __restrict__ scale,  // [32,2]
        const float* __restrict__ shift,  // [32,2]
        const float* __restrict__ w_out,  // [1,2]
        const float* __restrict__ b_out,  // [1]
        float* __restrict__ out)          // [B,1]
{
    __shared__ float sP[LAYERS * 8];  // per layer: m00,m01,m10,m11,C0,C1,pad,pad
    __shared__ float sF[4];           // Mo0, Mo1, Co, pad

    const int t = threadIdx.x;
    const float c = 2.885390081777927f;  // 2*log2(e)

    if (t < LAYERS) {
        float w00 = W[t*4+0], w01 = W[t*4+1], w10 = W[t*4+2], w11 = W[t*4+3];
        float b0 = b[t*2+0], b1 = b[t*2+1];
        float m00, m01, m10, m11, C0, C1;
        if (t > 0) {
            float s0 = scale[(t-1)*2+0], s1 = scale[(t-1)*2+1];
            float u0 = s0 + shift[(t-1)*2+0], u1 = s1 + shift[(t-1)*2+1];
            C0 = c * (b0 + w00*u0 + w01*u1);
            C1 = c * (b1 + w10*u0 + w11*u1);
            float k = -2.0f * c;
            m00 = k*w00*s0; m01 = k*w01*s1;
            m10 = k*w10*s0; m11 = k*w11*s1;
        } else {
            C0 = c*b0; C1 = c*b1;
            m00 = c*w00; m01 = c*w01; m10 = c*w10; m11 = c*w11;
        }
        sP[t*8+0] = m00; sP[t*8+1] = m01;
        sP[t*8+2] = m10; sP[t*8+3] = m11;
        sP[t*8+4] = C0;  sP[t*8+5] = C1;
        sP[t*8+6] = 0.f; sP[t*8+7] = 0.f;
    } else if (t == LAYERS) {
        float s0 = scale[31*2+0], s1 = scale[31*2+1];
        float u0 = s0 + shift[31*2+0], u1 = s1 + shift[31*2+1];
        float wo0 = w_out[0], wo1 = w_out[1];
        sF[0] = -2.0f * wo0 * s0;
        sF[1] = -2.0f * wo1 * s1;
        sF[2] = b_out[0] + wo0*u0 + wo1*u1;
        sF[3] = 0.f;
    }
    __syncthreads();

    const float4* __restrict__ xv = (const float4*)x;   // one float4 = 2 rows
    float2*       __restrict__ ov = (float2*)out;       // one float2 = 2 rows' outputs
    const int base4 = blockIdx.x * (BLOCK * R4) + t;    // block-interleaved -> coalesced

    float gx[2*R4], gy[2*R4];

    // Layer 0: from raw x (loads issue back-to-back; latency paid once).
    {
        const float4 m0 = *(const float4*)&sP[0];
        const float C0 = sP[4], C1 = sP[5];
        #pragma unroll
        for (int i = 0; i < R4; ++i) {
            float4 a = xv[base4 + i*BLOCK];
            layer_g(a.x, a.y, m0, C0, C1, gx[2*i+0], gy[2*i+0]);
            layer_g(a.z, a.w, m0, C0, C1, gx[2*i+1], gy[2*i+1]);
        }
    }

    // Layers 1..31. unroll 4: pipelines next-layer ds_reads under math, ~4KB body.
    #pragma unroll 4
    for (int l = 1; l < LAYERS; ++l) {
        const float4 m  = *(const float4*)&sP[l*8];
        const float C0 = sP[l*8+4];
        const float C1 = sP[l*8+5];
        #pragma unroll
        for (int r = 0; r < 2*R4; ++r) {
            layer_g(gx[r], gy[r], m, C0, C1, gx[r], gy[r]);
        }
    }

    // Output fold: out = Co + Mo0*gx + Mo1*gy
    const float Mo0 = sF[0], Mo1 = sF[1], Co = sF[2];
    #pragma unroll
    for (int i = 0; i < R4; ++i) {
        float2 o;
        o.x = fmaf(gx[2*i+0], Mo0, fmaf(gy[2*i+0], Mo1, Co));
        o.y = fmaf(gx[2*i+1], Mo0, fmaf(gy[2*i+1], Mo1, Co));
        ov[base4 + i*BLOCK] = o;
    }
}

extern "C" void kernel_launch(void* const* d_in, const int* in_sizes, int n_in,
                              void* d_out, int out_size, void* d_ws, size_t ws_size,
                              hipStream_t stream) {
    const float* x     = (const float*)d_in[0];
    const float* W     = (const float*)d_in[1];
    const float* b     = (const float*)d_in[2];
    const float* scale = (const float*)d_in[3];
    const float* shift = (const float*)d_in[4];
    const float* w_out = (const float*)d_in[5];
    const float* b_out = (const float*)d_in[6];
    float* out = (float*)d_out;

    const int B = in_sizes[0] / 2;               // 8388608
    const int rows_per_block = BLOCK * R4 * 2;   // 4096
    const int blocks = B / rows_per_block;       // 2048

    fraud_fwd<<<blocks, BLOCK, 0, stream>>>(x, W, b, scale, shift, w_out, b_out, out);
}